// Round 3
// baseline (764.681 us; speedup 1.0000x reference)
//
#include <hip/hip_runtime.h>
#include <cstddef>

// Problem constants
#define NB 16
#define NVOX 128
#define VOL_PER_B (NVOX * NVOX * NVOX)   // 2097152
#define TOTVOX (NB * VOL_PER_B)          // 33554432
#define NPT 1920

static __device__ __forceinline__ float2 f2(float a, float b) {
    float2 r; r.x = a; r.y = b; return r;
}

// ---------------------------------------------------------------------------
// Fused MLP + trilinear splat. One block per batch, 1024 threads.
// ---------------------------------------------------------------------------
__global__ __launch_bounds__(1024)
void mlp_splat(const float* __restrict__ q, const float* __restrict__ qval,
               const float* __restrict__ w1, const float* __restrict__ b1,
               const float* __restrict__ w2, const float* __restrict__ b2,
               const float* __restrict__ w3, const float* __restrict__ b3,
               const float* __restrict__ w4, const float* __restrict__ b4,
               const float* __restrict__ w5, const float* __restrict__ b5,
               float2* __restrict__ acc)
{
    __shared__ __align__(16) float qsT[8 * 260];
    __shared__ float bufA[7680];
    __shared__ float bufC[3840];
    __shared__ float meanv[64], rstdv[64];
    __shared__ float m4[16], r4[16];

    const int b = blockIdx.x;
    const int t = threadIdx.x;

    const float* qb = q + b * 2048;
    for (int u = t; u < 2048; u += 1024) {
        int i = u >> 3, l = u & 7;
        qsT[l * 260 + i] = qb[u];
    }
    __syncthreads();

    for (int k = t; k < 1920; k += 1024) {
        int o = k >> 3, l = k & 7;
        const float4* wrow = (const float4*)(w1 + o * 256);
        const float4* xrow = (const float4*)(&qsT[l * 260]);
        float s0 = b1[o], s1 = 0.f, s2 = 0.f, s3 = 0.f;
        #pragma unroll 8
        for (int i = 0; i < 64; ++i) {
            float4 w = wrow[i];
            float4 x = xrow[i];
            s0 = fmaf(w.x, x.x, s0);
            s1 = fmaf(w.y, x.y, s1);
            s2 = fmaf(w.z, x.z, s2);
            s3 = fmaf(w.w, x.w, s3);
        }
        bufA[k] = (s0 + s1) + (s2 + s3);
    }
    __syncthreads();
    if (t < 64) {
        float s = 0.f, s2 = 0.f;
        for (int p = 0; p < 30; ++p) { float v = bufA[t * 30 + p]; s += v; s2 += v * v; }
        float m = s * (1.f / 30.f);
        float var = s2 * (1.f / 30.f) - m * m;
        meanv[t] = m; rstdv[t] = rsqrtf(var + 1e-5f);
    }
    __syncthreads();
    for (int k = t; k < 1920; k += 1024) {
        int c = k / 30;
        bufA[k] = fmaxf((bufA[k] - meanv[c]) * rstdv[c], 0.f);
    }
    __syncthreads();

    for (int m = t; m < 3840; m += 1024) {
        int c = m / 60;
        int r = m - c * 60;
        int j = r / 30;
        int p = r - j * 30;
        bufC[m] = fmaf(bufA[c * 30 + p], w2[c * 2 + j], b2[c * 2 + j]);
    }
    __syncthreads();
    if (t < 32) {
        float s = 0.f, s2 = 0.f;
        for (int p = 0; p < 120; ++p) { float v = bufC[t * 120 + p]; s += v; s2 += v * v; }
        float m = s * (1.f / 120.f);
        float var = s2 * (1.f / 120.f) - m * m;
        meanv[t] = m; rstdv[t] = rsqrtf(var + 1e-5f);
    }
    __syncthreads();
    for (int m = t; m < 3840; m += 1024) {
        int c = m / 120;
        bufC[m] = fmaxf((bufC[m] - meanv[c]) * rstdv[c], 0.f);
    }
    __syncthreads();

    for (int m = t; m < 7680; m += 1024) {
        int c = m / 240;
        int r = m - c * 240;
        int j = r / 120;
        int p = r - j * 120;
        bufA[m] = fmaf(bufC[c * 120 + p], w3[c * 2 + j], b3[c * 2 + j]);
    }
    __syncthreads();
    if (t < 16) {
        float s = 0.f, s2 = 0.f;
        for (int p = 0; p < 480; ++p) { float v = bufA[t * 480 + p]; s += v; s2 += v * v; }
        float m = s * (1.f / 480.f);
        float var = s2 * (1.f / 480.f) - m * m;
        meanv[t] = m; rstdv[t] = rsqrtf(var + 1e-5f);
    }
    __syncthreads();
    for (int m = t; m < 7680; m += 1024) {
        int c = m / 480;
        bufA[m] = fmaxf((bufA[m] - meanv[c]) * rstdv[c], 0.f);
    }
    __syncthreads();

    if (t < 16) {
        float s = 0.f, s2 = 0.f;
        for (int p = 0; p < 480; ++p) { float v = bufA[t * 480 + p]; s += v; s2 += v * v; }
        float sum4 = 0.f, sq4 = 0.f;
        for (int j = 0; j < 4; ++j) {
            float w = w4[t * 4 + j], bb = b4[t * 4 + j];
            sum4 += w * s + 480.f * bb;
            sq4  += w * w * s2 + 2.f * w * bb * s + 480.f * bb * bb;
        }
        float m = sum4 * (1.f / 1920.f);
        float var = sq4 * (1.f / 1920.f) - m * m;
        m4[t] = m; r4[t] = rsqrtf(var + 1e-5f);
    }
    __syncthreads();

    for (int l = t; l < NPT; l += 1024) {
        int j = l / 480;
        int p = l - j * 480;
        float a0 = b5[0], a1 = b5[1], a2 = b5[2];
        #pragma unroll
        for (int c = 0; c < 16; ++c) {
            float xv = bufA[c * 480 + p];
            float x4 = fmaf(xv, w4[c * 4 + j], b4[c * 4 + j]);
            float h  = fmaxf((x4 - m4[c]) * r4[c], 0.f);
            a0 = fmaf(w5[c],      h, a0);
            a1 = fmaf(w5[16 + c], h, a1);
            a2 = fmaf(w5[32 + c], h, a2);
        }
        float px = tanhf(a0) * 64.f + 63.5f;
        float py = tanhf(a1) * 64.f + 63.5f;
        float pz = tanhf(a2) * 64.f + 63.5f;
        float val = 1.f / (1.f + expf(-qval[l]));

        float x0f = floorf(px), y0f = floorf(py), z0f = floorf(pz);
        float fx = px - x0f, fy = py - y0f, fz = pz - z0f;
        int x0 = (int)x0f, y0 = (int)y0f, z0 = (int)z0f;
        for (int dz = 0; dz < 2; ++dz) {
            int zi = z0 + dz;
            if (zi < 0 || zi >= NVOX) continue;
            float wz = dz ? fz : 1.f - fz;
            for (int dy = 0; dy < 2; ++dy) {
                int yi = y0 + dy;
                if (yi < 0 || yi >= NVOX) continue;
                float wy = dy ? fy : 1.f - fy;
                for (int dx = 0; dx < 2; ++dx) {
                    int xi = x0 + dx;
                    if (xi < 0 || xi >= NVOX) continue;
                    float wx = dx ? fx : 1.f - fx;
                    float w = wx * wy * wz;
                    int idx = ((b * NVOX + zi) * NVOX + yi) * NVOX + xi;
                    atomicAdd(&acc[idx].x, w * val);
                    atomicAdd(&acc[idx].y, w);
                }
            }
        }
    }
}

// ---------------------------------------------------------------------------
// 7-tap helper: taps (v0..v6) at offsets -3..+3, outer coeffs fixed 1,3 / 3,1;
// cm1/c0/cp1 are the position-dependent inner coefficients. Applies 1/27.
// ---------------------------------------------------------------------------
__device__ __forceinline__ float4 w7v(float4 v0, float4 v1, float4 v2, float4 v3,
                                      float4 v4, float4 v5, float4 v6,
                                      float cm1, float c0, float cp1)
{
    float4 r;
    r.x = ((v0.x + v6.x) + 3.f * (v1.x + v5.x) + cm1 * v2.x + c0 * v3.x + cp1 * v4.x) * (1.f / 27.f);
    r.y = ((v0.y + v6.y) + 3.f * (v1.y + v5.y) + cm1 * v2.y + c0 * v3.y + cp1 * v4.y) * (1.f / 27.f);
    r.z = ((v0.z + v6.z) + 3.f * (v1.z + v5.z) + cm1 * v2.z + c0 * v3.z + cp1 * v4.z) * (1.f / 27.f);
    r.w = ((v0.w + v6.w) + 3.f * (v1.w + v5.w) + cm1 * v2.w + c0 * v3.w + cp1 * v4.w) * (1.f / 27.f);
    return r;
}

// ---------------------------------------------------------------------------
// Z-axis pass, half-lines: each thread computes 64 outputs along z (halo
// re-read 70/64). 262144 threads = 4096 waves = 16 waves/CU.
// ---------------------------------------------------------------------------
__global__ __launch_bounds__(256)
void smooth_z(const float4* __restrict__ in, float4* __restrict__ out)
{
    const int S = 8192;                       // z stride in float4 units
    int T = blockIdx.x * 256 + threadIdx.x;   // 262144 threads
    int x2 = T & 63;
    int h  = (T >> 6) & 1;                    // wave-uniform
    int hi = (T >> 7) & 127;                  // y
    int b  = T >> 14;
    int base = b * (VOL_PER_B / 2) + hi * 64 + x2;
    const float4* ip = in + base;
    float4* op = out + base;

    const float4 z = make_float4(0.f, 0.f, 0.f, 0.f);
    if (h == 0) {
        // outputs z = 0..63
        float4 v0 = z, v1 = z, v2 = z;
        float4 v3 = ip[0], v4 = ip[S], v5 = ip[2 * S];
        {
            float4 a  = ip[3 * S];
            float4 bb = ip[4 * S];
            op[0] = w7v(v0, v1, v2, v3, v4, v5, a, 6.f, 4.f, 5.f);
            op[S] = w7v(v1, v2, v3, v4, v5, a, bb, 5.f, 7.f, 6.f);
            v0 = v2; v1 = v3; v2 = v4; v3 = v5; v4 = a; v5 = bb;
        }
        #pragma unroll 4
        for (int i = 2; i < 64; i += 2) {
            float4 a  = ip[(i + 3) * S];
            float4 bb = ip[(i + 4) * S];
            op[i * S]       = w7v(v0, v1, v2, v3, v4, v5, a, 6.f, 7.f, 6.f);
            op[(i + 1) * S] = w7v(v1, v2, v3, v4, v5, a, bb, 6.f, 7.f, 6.f);
            v0 = v2; v1 = v3; v2 = v4; v3 = v5; v4 = a; v5 = bb;
        }
    } else {
        // outputs z = 64..127; first output needs taps 61..67
        float4 v0 = ip[61 * S], v1 = ip[62 * S], v2 = ip[63 * S];
        float4 v3 = ip[64 * S], v4 = ip[65 * S], v5 = ip[66 * S];
        #pragma unroll 4
        for (int i = 64; i < 124; i += 2) {
            float4 a  = ip[(i + 3) * S];
            float4 bb = ip[(i + 4) * S];
            op[i * S]       = w7v(v0, v1, v2, v3, v4, v5, a, 6.f, 7.f, 6.f);
            op[(i + 1) * S] = w7v(v1, v2, v3, v4, v5, a, bb, 6.f, 7.f, 6.f);
            v0 = v2; v1 = v3; v2 = v4; v3 = v5; v4 = a; v5 = bb;
        }
        {
            float4 a  = ip[127 * S];
            float4 bb = z;
            op[124 * S] = w7v(v0, v1, v2, v3, v4, v5, a, 6.f, 7.f, 6.f);
            op[125 * S] = w7v(v1, v2, v3, v4, v5, a, bb, 6.f, 7.f, 6.f);
            v0 = v2; v1 = v3; v2 = v4; v3 = v5; v4 = a; v5 = bb;
        }
        {
            float4 a = z, bb = z;
            op[126 * S] = w7v(v0, v1, v2, v3, v4, v5, a, 6.f, 7.f, 5.f);
            op[127 * S] = w7v(v1, v2, v3, v4, v5, a, bb, 5.f, 4.f, 6.f);
        }
    }
}

// ---------------------------------------------------------------------------
// Fused y-smooth + x-smooth + division. One block per (b,z) plane x-strip.
// Strip: output x in [32s, 32s+32), input x in [32s-3, 32s+35) (zero-filled
// outside). LDS: raw strip 128x38 float2 + y-smoothed strip 128x38 float2.
// ---------------------------------------------------------------------------
__global__ __launch_bounds__(256)
void smooth_yx_div(const float2* __restrict__ in, float* __restrict__ out)
{
    __shared__ float2 in_t[128 * 38];   // [y][xx]
    __shared__ float2 ys[128 * 38];     // y-smoothed

    const int t = threadIdx.x;
    const int s     = blockIdx.x & 3;          // x-strip
    const int plane = blockIdx.x >> 2;         // b*128 + z
    const float2* gp = in + (size_t)plane * 16384;
    const int xbase = s * 32 - 3;

    // load strip (zero-fill x outside [0,128))
    for (int u = t; u < 128 * 38; u += 256) {
        int y  = u / 38;
        int xx = u - y * 38;
        int gx = xbase + xx;
        float2 v = f2(0.f, 0.f);
        if ((unsigned)gx < 128u) v = gp[y * 128 + gx];
        in_t[u] = v;
    }
    __syncthreads();

    // y-smooth all 38 columns
    for (int u = t; u < 128 * 38; u += 256) {
        int y  = u / 38;
        int xx = u - y * 38;
        float cm1 = (y == 1 || y == 127) ? 5.f : 6.f;
        float c0  = (y == 0 || y == 127) ? 4.f : 7.f;
        float cp1 = (y == 0 || y == 126) ? 5.f : 6.f;
        float sx = 0.f, sy = 0.f;
        {
            int yv;
            float2 tv;
            yv = y - 3; if ((unsigned)yv < 128u) { tv = in_t[yv * 38 + xx]; sx += tv.x; sy += tv.y; }
            yv = y + 3; if ((unsigned)yv < 128u) { tv = in_t[yv * 38 + xx]; sx += tv.x; sy += tv.y; }
            float ax = 0.f, ay = 0.f;
            yv = y - 2; if ((unsigned)yv < 128u) { tv = in_t[yv * 38 + xx]; ax += tv.x; ay += tv.y; }
            yv = y + 2; if ((unsigned)yv < 128u) { tv = in_t[yv * 38 + xx]; ax += tv.x; ay += tv.y; }
            sx += 3.f * ax; sy += 3.f * ay;
            yv = y - 1; if ((unsigned)yv < 128u) { tv = in_t[yv * 38 + xx]; sx = fmaf(cm1, tv.x, sx); sy = fmaf(cm1, tv.y, sy); }
            tv = in_t[y * 38 + xx]; sx = fmaf(c0, tv.x, sx); sy = fmaf(c0, tv.y, sy);
            yv = y + 1; if ((unsigned)yv < 128u) { tv = in_t[yv * 38 + xx]; sx = fmaf(cp1, tv.x, sx); sy = fmaf(cp1, tv.y, sy); }
        }
        ys[u] = f2(sx * (1.f / 27.f), sy * (1.f / 27.f));
    }
    __syncthreads();

    // x-smooth central 32 columns + division, write output
    float* ob = out + (size_t)plane * 16384;
    for (int u = t; u < 128 * 32; u += 256) {
        int y = u >> 5;
        int x = u & 31;
        int gx = s * 32 + x;
        float cm1 = (gx == 1 || gx == 127) ? 5.f : 6.f;
        float c0  = (gx == 0 || gx == 127) ? 4.f : 7.f;
        float cp1 = (gx == 0 || gx == 126) ? 5.f : 6.f;
        const float2* L = &ys[y * 38 + x + 3];   // center tap
        float sa = (L[-3].x + L[3].x) + 3.f * (L[-2].x + L[2].x)
                 + cm1 * L[-1].x + c0 * L[0].x + cp1 * L[1].x;
        float sb = (L[-3].y + L[3].y) + 3.f * (L[-2].y + L[2].y)
                 + cm1 * L[-1].y + c0 * L[0].y + cp1 * L[1].y;
        ob[y * 128 + gx] = (sa * (1.f / 27.f)) / (sb * (1.f / 27.f) + 0.001f);
    }
}

// ---------------------------------------------------------------------------
extern "C" void kernel_launch(void* const* d_in, const int* in_sizes, int n_in,
                              void* d_out, int out_size, void* d_ws, size_t ws_size,
                              hipStream_t stream)
{
    const float* q    = (const float*)d_in[0];
    const float* qval = (const float*)d_in[1];
    const float* w1   = (const float*)d_in[2];
    const float* b1   = (const float*)d_in[3];
    const float* w2   = (const float*)d_in[4];
    const float* b2   = (const float*)d_in[5];
    const float* w3   = (const float*)d_in[6];
    const float* b3   = (const float*)d_in[7];
    const float* w4   = (const float*)d_in[8];
    const float* b4   = (const float*)d_in[9];
    const float* w5   = (const float*)d_in[10];
    const float* b5   = (const float*)d_in[11];
    float* out = (float*)d_out;

    float2* buf0 = (float2*)d_ws;
    float2* buf1 = buf0 + (size_t)TOTVOX;

    hipMemsetAsync(buf0, 0, (size_t)TOTVOX * sizeof(float2), stream);

    mlp_splat<<<NB, 1024, 0, stream>>>(q, qval, w1, b1, w2, b2, w3, b3,
                                       w4, b4, w5, b5, buf0);

    // z-axis pass (half-lines, 2x wave count)
    smooth_z<<<262144 / 256, 256, 0, stream>>>((const float4*)buf0, (float4*)buf1);

    // fused y + x + division
    smooth_yx_div<<<16 * 128 * 4, 256, 0, stream>>>(buf1, out);
}

// Round 4
// 333.871 us; speedup vs baseline: 2.2904x; 2.2904x over previous
//
#include <hip/hip_runtime.h>
#include <cstddef>

// Problem constants
#define NB 16
#define NVOX 128
#define NPT 1920

static __device__ __forceinline__ float2 f2(float a, float b) {
    float2 r; r.x = a; r.y = b; return r;
}

// ---------------------------------------------------------------------------
// Fused MLP -> point list + active-tile flags. One block per batch, 1024 thr.
// ---------------------------------------------------------------------------
__global__ __launch_bounds__(1024)
void mlp_points(const float* __restrict__ q, const float* __restrict__ qval,
                const float* __restrict__ w1, const float* __restrict__ b1,
                const float* __restrict__ w2, const float* __restrict__ b2,
                const float* __restrict__ w3, const float* __restrict__ b3,
                const float* __restrict__ w4, const float* __restrict__ b4,
                const float* __restrict__ w5, const float* __restrict__ b5,
                float4* __restrict__ pts, unsigned char* __restrict__ flags)
{
    __shared__ __align__(16) float qsT[8 * 260];
    __shared__ float bufA[7680];
    __shared__ float bufC[3840];
    __shared__ float meanv[64], rstdv[64];
    __shared__ float m4[16], r4[16];

    const int b = blockIdx.x;
    const int t = threadIdx.x;

    const float* qb = q + b * 2048;
    for (int u = t; u < 2048; u += 1024) {
        int i = u >> 3, l = u & 7;
        qsT[l * 260 + i] = qb[u];
    }
    __syncthreads();

    // stage1: Conv1d(256,240) on (256,8) view
    for (int k = t; k < 1920; k += 1024) {
        int o = k >> 3, l = k & 7;
        const float4* wrow = (const float4*)(w1 + o * 256);
        const float4* xrow = (const float4*)(&qsT[l * 260]);
        float s0 = b1[o], s1 = 0.f, s2 = 0.f, s3 = 0.f;
        #pragma unroll 8
        for (int i = 0; i < 64; ++i) {
            float4 w = wrow[i];
            float4 x = xrow[i];
            s0 = fmaf(w.x, x.x, s0);
            s1 = fmaf(w.y, x.y, s1);
            s2 = fmaf(w.z, x.z, s2);
            s3 = fmaf(w.w, x.w, s3);
        }
        bufA[k] = (s0 + s1) + (s2 + s3);
    }
    __syncthreads();
    if (t < 64) {
        float s = 0.f, s2 = 0.f;
        for (int p = 0; p < 30; ++p) { float v = bufA[t * 30 + p]; s += v; s2 += v * v; }
        float m = s * (1.f / 30.f);
        float var = s2 * (1.f / 30.f) - m * m;
        meanv[t] = m; rstdv[t] = rsqrtf(var + 1e-5f);
    }
    __syncthreads();
    for (int k = t; k < 1920; k += 1024) {
        int c = k / 30;
        bufA[k] = fmaxf((bufA[k] - meanv[c]) * rstdv[c], 0.f);
    }
    __syncthreads();

    for (int m = t; m < 3840; m += 1024) {
        int c = m / 60;
        int r = m - c * 60;
        int j = r / 30;
        int p = r - j * 30;
        bufC[m] = fmaf(bufA[c * 30 + p], w2[c * 2 + j], b2[c * 2 + j]);
    }
    __syncthreads();
    if (t < 32) {
        float s = 0.f, s2 = 0.f;
        for (int p = 0; p < 120; ++p) { float v = bufC[t * 120 + p]; s += v; s2 += v * v; }
        float m = s * (1.f / 120.f);
        float var = s2 * (1.f / 120.f) - m * m;
        meanv[t] = m; rstdv[t] = rsqrtf(var + 1e-5f);
    }
    __syncthreads();
    for (int m = t; m < 3840; m += 1024) {
        int c = m / 120;
        bufC[m] = fmaxf((bufC[m] - meanv[c]) * rstdv[c], 0.f);
    }
    __syncthreads();

    for (int m = t; m < 7680; m += 1024) {
        int c = m / 240;
        int r = m - c * 240;
        int j = r / 120;
        int p = r - j * 120;
        bufA[m] = fmaf(bufC[c * 120 + p], w3[c * 2 + j], b3[c * 2 + j]);
    }
    __syncthreads();
    if (t < 16) {
        float s = 0.f, s2 = 0.f;
        for (int p = 0; p < 480; ++p) { float v = bufA[t * 480 + p]; s += v; s2 += v * v; }
        float m = s * (1.f / 480.f);
        float var = s2 * (1.f / 480.f) - m * m;
        meanv[t] = m; rstdv[t] = rsqrtf(var + 1e-5f);
    }
    __syncthreads();
    for (int m = t; m < 7680; m += 1024) {
        int c = m / 480;
        bufA[m] = fmaxf((bufA[m] - meanv[c]) * rstdv[c], 0.f);
    }
    __syncthreads();

    // stage4 IN stats analytically
    if (t < 16) {
        float s = 0.f, s2 = 0.f;
        for (int p = 0; p < 480; ++p) { float v = bufA[t * 480 + p]; s += v; s2 += v * v; }
        float sum4 = 0.f, sq4 = 0.f;
        for (int j = 0; j < 4; ++j) {
            float w = w4[t * 4 + j], bb = b4[t * 4 + j];
            sum4 += w * s + 480.f * bb;
            sq4  += w * w * s2 + 2.f * w * bb * s + 480.f * bb * bb;
        }
        float m = sum4 * (1.f / 1920.f);
        float var = sq4 * (1.f / 1920.f) - m * m;
        m4[t] = m; r4[t] = rsqrtf(var + 1e-5f);
    }
    __syncthreads();

    for (int l = t; l < NPT; l += 1024) {
        int j = l / 480;
        int p = l - j * 480;
        float a0 = b5[0], a1 = b5[1], a2 = b5[2];
        #pragma unroll
        for (int c = 0; c < 16; ++c) {
            float xv = bufA[c * 480 + p];
            float x4 = fmaf(xv, w4[c * 4 + j], b4[c * 4 + j]);
            float h  = fmaxf((x4 - m4[c]) * r4[c], 0.f);
            a0 = fmaf(w5[c],      h, a0);
            a1 = fmaf(w5[16 + c], h, a1);
            a2 = fmaf(w5[32 + c], h, a2);
        }
        float px = tanhf(a0) * 64.f + 63.5f;
        float py = tanhf(a1) * 64.f + 63.5f;
        float pz = tanhf(a2) * 64.f + 63.5f;
        float val = 1.f / (1.f + expf(-qval[l]));

        float4 pv; pv.x = px; pv.y = py; pv.z = pz; pv.w = val;
        pts[b * NPT + l] = pv;

        // mark affected 8^3 tiles: outputs in [c0-3, c0+4] per axis
        int x0 = (int)floorf(px), y0 = (int)floorf(py), z0 = (int)floorf(pz);
        int xlo = max(0, x0 - 3), xhi = min(127, x0 + 4);
        int ylo = max(0, y0 - 3), yhi = min(127, y0 + 4);
        int zlo = max(0, z0 - 3), zhi = min(127, z0 + 4);
        if (xlo > xhi || ylo > yhi || zlo > zhi) continue;
        int txl = xlo >> 3, txh = xhi >> 3;
        int tyl = ylo >> 3, tyh = yhi >> 3;
        int tzl = zlo >> 3, tzh = zhi >> 3;
        for (int tz = tzl; tz <= tzh; ++tz)
            for (int ty = tyl; ty <= tyh; ++ty)
                for (int tx = txl; tx <= txh; ++tx)
                    flags[((b * 16 + tz) * 16 + ty) * 16 + tx] = 1;
    }
}

// ---------------------------------------------------------------------------
// Per-axis composed 7-tap coefficients (A^3, zero-padded 3-tap average):
// interior [1,3,6,7,6,3,1]/27; boundary rows via cm1/c0/cp1 overrides.
// ---------------------------------------------------------------------------
__device__ __forceinline__ void coef(int g, float& cm1, float& c0, float& cp1)
{
    cm1 = (g == 1 || g == 127) ? 5.f : 6.f;
    c0  = (g == 0 || g == 127) ? 4.f : 7.f;
    cp1 = (g == 0 || g == 126) ? 5.f : 6.f;
}

// ---------------------------------------------------------------------------
// Sparse tile kernel: one block per 16x8x8 output region (two 8^3 tiles in x).
// Inactive -> write zeros. Active -> splat points into 22x14x14 LDS tile,
// smooth z/y/x in LDS, divide, store.
// ---------------------------------------------------------------------------
__global__ __launch_bounds__(512)
void tile_smooth(const float4* __restrict__ pts,
                 const unsigned char* __restrict__ flags,
                 float* __restrict__ out)
{
    // raw: [z14][y14][x22]; reused as ys [z8][y8][x22] after z-pass consumed
    __shared__ float2 raw[14 * 14 * 22];   // 34496 B
    __shared__ float2 zs[8 * 14 * 22];     // 19712 B

    const int t = threadIdx.x;
    const int pair = blockIdx.x & 7;
    const int ty   = (blockIdx.x >> 3) & 15;
    const int tz   = (blockIdx.x >> 7) & 15;
    const int b    = blockIdx.x >> 11;
    const int Tx = pair * 16, Ty = ty * 8, Tz = tz * 8;

    const int fbase = ((b * 16 + tz) * 16 + ty) * 16 + 2 * pair;
    const int active = flags[fbase] | flags[fbase + 1];

    float* ob = out + (((size_t)(b * NVOX + Tz) * NVOX + Ty) * NVOX + Tx);

    if (!active) {
        // zero-fill 16x8x8 region; rows of 64 B
        int o = t * 2;                 // 0..1022
        int x = o & 15, y = (o >> 4) & 7, z = o >> 7;
        float2* p = (float2*)(ob + ((size_t)z * NVOX + y) * NVOX + x);
        *p = f2(0.f, 0.f);
        return;
    }

    // zero raw tile
    for (int u = t; u < 14 * 14 * 22; u += 512) raw[u] = f2(0.f, 0.f);
    __syncthreads();

    // scatter this batch's points into the tile (raw covers [T-3, T+{19,11,11}))
    const float4* pb = pts + b * NPT;
    for (int p = t; p < NPT; p += 512) {
        float4 pt = pb[p];
        float x0f = floorf(pt.x), y0f = floorf(pt.y), z0f = floorf(pt.z);
        int x0 = (int)x0f, y0 = (int)y0f, z0 = (int)z0f;
        int lx0 = x0 - Tx + 3, ly0 = y0 - Ty + 3, lz0 = z0 - Tz + 3;
        // reject if splat (2 voxels/axis) misses the tile's input region
        if (lx0 + 1 < 0 || lx0 > 21 || ly0 + 1 < 0 || ly0 > 13 ||
            lz0 + 1 < 0 || lz0 > 13) continue;
        float fx = pt.x - x0f, fy = pt.y - y0f, fz = pt.z - z0f;
        float val = pt.w;
        #pragma unroll
        for (int dz = 0; dz < 2; ++dz) {
            int zi = z0 + dz, lz = lz0 + dz;
            if ((unsigned)zi >= 128u || (unsigned)lz >= 14u) continue;
            float wz = dz ? fz : 1.f - fz;
            #pragma unroll
            for (int dy = 0; dy < 2; ++dy) {
                int yi = y0 + dy, ly = ly0 + dy;
                if ((unsigned)yi >= 128u || (unsigned)ly >= 14u) continue;
                float wy = dy ? fy : 1.f - fy;
                #pragma unroll
                for (int dx = 0; dx < 2; ++dx) {
                    int xi = x0 + dx, lx = lx0 + dx;
                    if ((unsigned)xi >= 128u || (unsigned)lx >= 22u) continue;
                    float w = (dx ? fx : 1.f - fx) * wy * wz;
                    float2* cell = &raw[(lz * 14 + ly) * 22 + lx];
                    atomicAdd(&cell->x, w * val);
                    atomicAdd(&cell->y, w);
                }
            }
        }
    }
    __syncthreads();

    // z-pass: raw [z14][y14][x22] -> zs [z8][y14][x22]
    for (int u = t; u < 8 * 14 * 22; u += 512) {
        int lx = u % 22;
        int tmp = u / 22;
        int ly = tmp % 14;
        int lz = tmp / 14;
        float cm1, c0, cp1; coef(Tz + lz, cm1, c0, cp1);
        const float2* a = &raw[(lz * 14 + ly) * 22 + lx];  // taps lz..lz+6
        const int S = 14 * 22;
        float sx = (a[0].x + a[6 * S].x) + 3.f * (a[S].x + a[5 * S].x)
                 + cm1 * a[2 * S].x + c0 * a[3 * S].x + cp1 * a[4 * S].x;
        float sy = (a[0].y + a[6 * S].y) + 3.f * (a[S].y + a[5 * S].y)
                 + cm1 * a[2 * S].y + c0 * a[3 * S].y + cp1 * a[4 * S].y;
        zs[u] = f2(sx * (1.f / 27.f), sy * (1.f / 27.f));
    }
    __syncthreads();

    // y-pass: zs [z8][y14][x22] -> ys (=raw) [z8][y8][x22]
    float2* ys = raw;
    for (int u = t; u < 8 * 8 * 22; u += 512) {
        int lx = u % 22;
        int tmp = u / 22;
        int ly = tmp % 8;
        int lz = tmp / 8;
        float cm1, c0, cp1; coef(Ty + ly, cm1, c0, cp1);
        const float2* a = &zs[(lz * 14 + ly) * 22 + lx];  // taps ly..ly+6
        const int S = 22;
        float sx = (a[0].x + a[6 * S].x) + 3.f * (a[S].x + a[5 * S].x)
                 + cm1 * a[2 * S].x + c0 * a[3 * S].x + cp1 * a[4 * S].x;
        float sy = (a[0].y + a[6 * S].y) + 3.f * (a[S].y + a[5 * S].y)
                 + cm1 * a[2 * S].y + c0 * a[3 * S].y + cp1 * a[4 * S].y;
        ys[(lz * 8 + ly) * 22 + lx] = f2(sx * (1.f / 27.f), sy * (1.f / 27.f));
    }
    __syncthreads();

    // x-pass + division, write 16x8x8 outputs
    for (int u = t; u < 16 * 8 * 8; u += 512) {
        int x = u & 15, y = (u >> 4) & 7, z = u >> 7;
        float cm1, c0, cp1; coef(Tx + x, cm1, c0, cp1);
        const float2* a = &ys[(z * 8 + y) * 22 + x];  // taps x..x+6
        float sx = (a[0].x + a[6].x) + 3.f * (a[1].x + a[5].x)
                 + cm1 * a[2].x + c0 * a[3].x + cp1 * a[4].x;
        float sy = (a[0].y + a[6].y) + 3.f * (a[1].y + a[5].y)
                 + cm1 * a[2].y + c0 * a[3].y + cp1 * a[4].y;
        ob[((size_t)z * NVOX + y) * NVOX + x] =
            (sx * (1.f / 27.f)) / (sy * (1.f / 27.f) + 0.001f);
    }
}

// ---------------------------------------------------------------------------
extern "C" void kernel_launch(void* const* d_in, const int* in_sizes, int n_in,
                              void* d_out, int out_size, void* d_ws, size_t ws_size,
                              hipStream_t stream)
{
    const float* q    = (const float*)d_in[0];
    const float* qval = (const float*)d_in[1];
    const float* w1   = (const float*)d_in[2];
    const float* b1   = (const float*)d_in[3];
    const float* w2   = (const float*)d_in[4];
    const float* b2   = (const float*)d_in[5];
    const float* w3   = (const float*)d_in[6];
    const float* b3   = (const float*)d_in[7];
    const float* w4   = (const float*)d_in[8];
    const float* b4   = (const float*)d_in[9];
    const float* w5   = (const float*)d_in[10];
    const float* b5   = (const float*)d_in[11];
    float* out = (float*)d_out;

    // ws layout: [0,64K) tile flags ; [64K, 64K+480K) point list
    unsigned char* flags = (unsigned char*)d_ws;
    float4* pts = (float4*)((char*)d_ws + 65536);

    hipMemsetAsync(flags, 0, 65536, stream);

    mlp_points<<<NB, 1024, 0, stream>>>(q, qval, w1, b1, w2, b2, w3, b3,
                                        w4, b4, w5, b5, pts, flags);

    // 16 batches x 16 tz x 16 ty x 8 x-pairs = 32768 blocks
    tile_smooth<<<32768, 512, 0, stream>>>(pts, flags, out);
}

// Round 5
// 252.127 us; speedup vs baseline: 3.0329x; 1.3242x over previous
//
#include <hip/hip_runtime.h>
#include <cstddef>

// Problem constants
#define NB 16
#define NVOX 128
#define NPT 1920
#define NPAIRS 32768   // 16 b * 16 tz * 16 ty * 8 x-pairs

static __device__ __forceinline__ float2 f2(float a, float b) {
    float2 r; r.x = a; r.y = b; return r;
}

// ---------------------------------------------------------------------------
// Zero the whole output at full write BW. grid 4096 x 256, float4 stores.
// ---------------------------------------------------------------------------
__global__ __launch_bounds__(256)
void zero_out(float4* __restrict__ out)
{
    int idx = blockIdx.x * 2048 + threadIdx.x;
    #pragma unroll
    for (int i = 0; i < 8; ++i)
        out[idx + i * 256] = make_float4(0.f, 0.f, 0.f, 0.f);
}

// ---------------------------------------------------------------------------
// Stage 1: Conv1d(256,240,1) on the (256,8) view, all 16 batches.
// One block per output channel o (240 blocks). w1 row staged coalesced in LDS;
// thread = (half, b, l) computes a split-K partial; pair-combined at the end.
// x1g layout: [b][o*8+l]  (matches (240,8) == (64,30) flat view downstream).
// ---------------------------------------------------------------------------
__global__ __launch_bounds__(256)
void mlp_stage1(const float* __restrict__ q, const float* __restrict__ w1,
                const float* __restrict__ b1, float* __restrict__ x1g)
{
    __shared__ float wrow[256];
    __shared__ float psum[256];
    const int o = blockIdx.x;
    const int t = threadIdx.x;

    wrow[t] = w1[o * 256 + t];
    __syncthreads();

    const int half = t >> 7;       // K-split: i in [half*128, half*128+128)
    const int bl = t & 127;
    const int b = bl >> 3, l = bl & 7;
    const float* qb = q + b * 2048 + l + half * 1024;  // q[b][i*8+l]
    float s = 0.f;
    #pragma unroll 8
    for (int i = 0; i < 128; ++i)
        s = fmaf(wrow[half * 128 + i], qb[i * 8], s);
    psum[t] = s;
    __syncthreads();

    if (t < 128) {
        int bb = t >> 3, ll = t & 7;
        x1g[bb * 1920 + o * 8 + ll] = b1[o] + psum[t] + psum[t + 128];
    }
}

// ---------------------------------------------------------------------------
// Tail: IN chains + grouped convs + point generation + active-tile flags.
// One block per batch, 256 threads. Parallel group reductions (G threads per
// channel, stride-G element access -> conflict-light).
// ---------------------------------------------------------------------------
__global__ __launch_bounds__(256)
void mlp_tail(const float* __restrict__ x1g, const float* __restrict__ qval,
              const float* __restrict__ w2, const float* __restrict__ b2,
              const float* __restrict__ w3, const float* __restrict__ b3,
              const float* __restrict__ w4, const float* __restrict__ b4,
              const float* __restrict__ w5, const float* __restrict__ b5,
              float4* __restrict__ pts, unsigned char* __restrict__ flags)
{
    __shared__ float bufA[7680];
    __shared__ float bufC[3840];
    __shared__ float psum[256], psq[256];
    __shared__ float meanv[64], rstdv[64];
    __shared__ float m4[16], r4[16];

    const int b = blockIdx.x;
    const int t = threadIdx.x;

    for (int u = t; u < 1920; u += 256) bufA[u] = x1g[b * 1920 + u];
    __syncthreads();

    // IN1 over (64,30): 4 threads/channel
    {
        int c = t >> 2, g = t & 3;
        float s = 0.f, s2 = 0.f;
        for (int p = g; p < 30; p += 4) { float v = bufA[c * 30 + p]; s += v; s2 += v * v; }
        psum[t] = s; psq[t] = s2;
    }
    __syncthreads();
    if (t < 64) {
        float s = 0.f, s2 = 0.f;
        for (int g = 0; g < 4; ++g) { s += psum[t * 4 + g]; s2 += psq[t * 4 + g]; }
        float m = s * (1.f / 30.f);
        float var = s2 * (1.f / 30.f) - m * m;
        meanv[t] = m; rstdv[t] = rsqrtf(var + 1e-5f);
    }
    __syncthreads();
    for (int k = t; k < 1920; k += 256) {
        int c = k / 30;
        bufA[k] = fmaxf((bufA[k] - meanv[c]) * rstdv[c], 0.f);
    }
    __syncthreads();

    // stage2: grouped conv 64->128, flat (32,120) in bufC
    for (int m = t; m < 3840; m += 256) {
        int c = m / 60;
        int r = m - c * 60;
        int j = r / 30;
        int p = r - j * 30;
        bufC[m] = fmaf(bufA[c * 30 + p], w2[c * 2 + j], b2[c * 2 + j]);
    }
    __syncthreads();
    // IN2 over (32,120): 8 threads/channel
    {
        int c = t >> 3, g = t & 7;
        float s = 0.f, s2 = 0.f;
        for (int p = g; p < 120; p += 8) { float v = bufC[c * 120 + p]; s += v; s2 += v * v; }
        psum[t] = s; psq[t] = s2;
    }
    __syncthreads();
    if (t < 32) {
        float s = 0.f, s2 = 0.f;
        for (int g = 0; g < 8; ++g) { s += psum[t * 8 + g]; s2 += psq[t * 8 + g]; }
        float m = s * (1.f / 120.f);
        float var = s2 * (1.f / 120.f) - m * m;
        meanv[t] = m; rstdv[t] = rsqrtf(var + 1e-5f);
    }
    __syncthreads();
    for (int m = t; m < 3840; m += 256) {
        int c = m / 120;
        bufC[m] = fmaxf((bufC[m] - meanv[c]) * rstdv[c], 0.f);
    }
    __syncthreads();

    // stage3: grouped conv 32->64, flat (16,480) in bufA
    for (int m = t; m < 7680; m += 256) {
        int c = m / 240;
        int r = m - c * 240;
        int j = r / 120;
        int p = r - j * 120;
        bufA[m] = fmaf(bufC[c * 120 + p], w3[c * 2 + j], b3[c * 2 + j]);
    }
    __syncthreads();

    // IN3 over (16,480): 16 threads/channel, 30 elems each
    const int c3 = t >> 4, g3 = t & 15;
    {
        float s = 0.f, s2 = 0.f;
        for (int k = 0; k < 30; ++k) { float v = bufA[c3 * 480 + g3 + 16 * k]; s += v; s2 += v * v; }
        psum[t] = s; psq[t] = s2;
    }
    __syncthreads();
    if (t < 16) {
        float s = 0.f, s2 = 0.f;
        for (int g = 0; g < 16; ++g) { s += psum[t * 16 + g]; s2 += psq[t * 16 + g]; }
        float m = s * (1.f / 480.f);
        float var = s2 * (1.f / 480.f) - m * m;
        meanv[t] = m; rstdv[t] = rsqrtf(var + 1e-5f);
    }
    __syncthreads();
    // normalize+relu in place, accumulate relu'd sums for stage4 stats
    {
        float m = meanv[c3], r = rstdv[c3];
        float s = 0.f, s2 = 0.f;
        for (int k = 0; k < 30; ++k) {
            int idx = c3 * 480 + g3 + 16 * k;
            float v = fmaxf((bufA[idx] - m) * r, 0.f);
            bufA[idx] = v; s += v; s2 += v * v;
        }
        psum[t] = s; psq[t] = s2;
    }
    __syncthreads();
    // stage4 IN stats analytically: x4[c, j*480+p] = x3n[c,p]*w4[c,j]+b4[c*4+j]
    if (t < 16) {
        float s = 0.f, s2 = 0.f;
        for (int g = 0; g < 16; ++g) { s += psum[t * 16 + g]; s2 += psq[t * 16 + g]; }
        float sum4 = 0.f, sq4 = 0.f;
        for (int j = 0; j < 4; ++j) {
            float w = w4[t * 4 + j], bb = b4[t * 4 + j];
            sum4 += w * s + 480.f * bb;
            sq4  += w * w * s2 + 2.f * w * bb * s + 480.f * bb * bb;
        }
        float m = sum4 * (1.f / 1920.f);
        float var = sq4 * (1.f / 1920.f) - m * m;
        m4[t] = m; r4[t] = rsqrtf(var + 1e-5f);
    }
    __syncthreads();

    // per-point: stage4 apply + stage5 einsum + tanh + emit point + mark tiles
    for (int l = t; l < NPT; l += 256) {
        int j = l / 480;
        int p = l - j * 480;
        float a0 = b5[0], a1 = b5[1], a2 = b5[2];
        #pragma unroll
        for (int c = 0; c < 16; ++c) {
            float xv = bufA[c * 480 + p];
            float x4 = fmaf(xv, w4[c * 4 + j], b4[c * 4 + j]);
            float h  = fmaxf((x4 - m4[c]) * r4[c], 0.f);
            a0 = fmaf(w5[c],      h, a0);
            a1 = fmaf(w5[16 + c], h, a1);
            a2 = fmaf(w5[32 + c], h, a2);
        }
        float px = tanhf(a0) * 64.f + 63.5f;
        float py = tanhf(a1) * 64.f + 63.5f;
        float pz = tanhf(a2) * 64.f + 63.5f;
        float val = 1.f / (1.f + expf(-qval[l]));

        float4 pv; pv.x = px; pv.y = py; pv.z = pz; pv.w = val;
        pts[b * NPT + l] = pv;

        int x0 = (int)floorf(px), y0 = (int)floorf(py), z0 = (int)floorf(pz);
        int xlo = max(0, x0 - 3), xhi = min(127, x0 + 4);
        int ylo = max(0, y0 - 3), yhi = min(127, y0 + 4);
        int zlo = max(0, z0 - 3), zhi = min(127, z0 + 4);
        if (xlo > xhi || ylo > yhi || zlo > zhi) continue;
        int txl = xlo >> 3, txh = xhi >> 3;
        int tyl = ylo >> 3, tyh = yhi >> 3;
        int tzl = zlo >> 3, tzh = zhi >> 3;
        for (int tz = tzl; tz <= tzh; ++tz)
            for (int ty = tyl; ty <= tyh; ++ty)
                for (int tx = txl; tx <= txh; ++tx)
                    flags[((b * 16 + tz) * 16 + ty) * 16 + tx] = 1;
    }
}

// ---------------------------------------------------------------------------
// Compact active tile-pairs (read flags as ushort: 2 tiles per x-pair).
// ---------------------------------------------------------------------------
__global__ __launch_bounds__(256)
void compact_tiles(const unsigned char* __restrict__ flags,
                   int* __restrict__ count, int* __restrict__ list)
{
    int i = blockIdx.x * 256 + threadIdx.x;   // pair index 0..32767
    const unsigned short* fp = (const unsigned short*)flags;
    if (fp[i] != 0) {
        int pos = atomicAdd(count, 1);
        list[pos] = i;
    }
}

// ---------------------------------------------------------------------------
// Per-axis composed 7-tap coefficients (A^3, zero-padded 3-tap average):
// interior [1,3,6,7,6,3,1]/27; boundary rows via cm1/c0/cp1 overrides.
// ---------------------------------------------------------------------------
__device__ __forceinline__ void coef(int g, float& cm1, float& c0, float& cp1)
{
    cm1 = (g == 1 || g == 127) ? 5.f : 6.f;
    c0  = (g == 0 || g == 127) ? 4.f : 7.f;
    cp1 = (g == 0 || g == 126) ? 5.f : 6.f;
}

// ---------------------------------------------------------------------------
// Active tile kernel: safe-bound grid (32768); blocks >= count exit.
// Splat points into 22x14x14 LDS tile, smooth z/y/x in LDS, divide, store.
// ---------------------------------------------------------------------------
__global__ __launch_bounds__(512)
void tile_active(const float4* __restrict__ pts, const int* __restrict__ count,
                 const int* __restrict__ list, float* __restrict__ out)
{
    __shared__ float2 raw[14 * 14 * 22];   // 34496 B  (reused as ys after y-pass)
    __shared__ float2 zs[8 * 14 * 22];     // 19712 B

    if ((int)blockIdx.x >= *count) return;
    const int code = list[blockIdx.x];
    const int pair = code & 7;
    const int ty   = (code >> 3) & 15;
    const int tz   = (code >> 7) & 15;
    const int b    = code >> 11;
    const int Tx = pair * 16, Ty = ty * 8, Tz = tz * 8;
    const int t = threadIdx.x;

    float* ob = out + (((size_t)(b * NVOX + Tz) * NVOX + Ty) * NVOX + Tx);

    for (int u = t; u < 14 * 14 * 22; u += 512) raw[u] = f2(0.f, 0.f);
    __syncthreads();

    // scatter this batch's points (raw covers [T-3, T+{19,11,11}))
    const float4* pb = pts + b * NPT;
    for (int p = t; p < NPT; p += 512) {
        float4 pt = pb[p];
        float x0f = floorf(pt.x), y0f = floorf(pt.y), z0f = floorf(pt.z);
        int x0 = (int)x0f, y0 = (int)y0f, z0 = (int)z0f;
        int lx0 = x0 - Tx + 3, ly0 = y0 - Ty + 3, lz0 = z0 - Tz + 3;
        if (lx0 + 1 < 0 || lx0 > 21 || ly0 + 1 < 0 || ly0 > 13 ||
            lz0 + 1 < 0 || lz0 > 13) continue;
        float fx = pt.x - x0f, fy = pt.y - y0f, fz = pt.z - z0f;
        float val = pt.w;
        #pragma unroll
        for (int dz = 0; dz < 2; ++dz) {
            int zi = z0 + dz, lz = lz0 + dz;
            if ((unsigned)zi >= 128u || (unsigned)lz >= 14u) continue;
            float wz = dz ? fz : 1.f - fz;
            #pragma unroll
            for (int dy = 0; dy < 2; ++dy) {
                int yi = y0 + dy, ly = ly0 + dy;
                if ((unsigned)yi >= 128u || (unsigned)ly >= 14u) continue;
                float wy = dy ? fy : 1.f - fy;
                #pragma unroll
                for (int dx = 0; dx < 2; ++dx) {
                    int xi = x0 + dx, lx = lx0 + dx;
                    if ((unsigned)xi >= 128u || (unsigned)lx >= 22u) continue;
                    float w = (dx ? fx : 1.f - fx) * wy * wz;
                    float2* cell = &raw[(lz * 14 + ly) * 22 + lx];
                    atomicAdd(&cell->x, w * val);
                    atomicAdd(&cell->y, w);
                }
            }
        }
    }
    __syncthreads();

    // z-pass: raw [z14][y14][x22] -> zs [z8][y14][x22]
    for (int u = t; u < 8 * 14 * 22; u += 512) {
        int lx = u % 22;
        int tmp = u / 22;
        int ly = tmp % 14;
        int lz = tmp / 14;
        float cm1, c0, cp1; coef(Tz + lz, cm1, c0, cp1);
        const float2* a = &raw[(lz * 14 + ly) * 22 + lx];
        const int S = 14 * 22;
        float sx = (a[0].x + a[6 * S].x) + 3.f * (a[S].x + a[5 * S].x)
                 + cm1 * a[2 * S].x + c0 * a[3 * S].x + cp1 * a[4 * S].x;
        float sy = (a[0].y + a[6 * S].y) + 3.f * (a[S].y + a[5 * S].y)
                 + cm1 * a[2 * S].y + c0 * a[3 * S].y + cp1 * a[4 * S].y;
        zs[u] = f2(sx * (1.f / 27.f), sy * (1.f / 27.f));
    }
    __syncthreads();

    // y-pass: zs [z8][y14][x22] -> ys (=raw) [z8][y8][x22]
    float2* ys = raw;
    for (int u = t; u < 8 * 8 * 22; u += 512) {
        int lx = u % 22;
        int tmp = u / 22;
        int ly = tmp % 8;
        int lz = tmp / 8;
        float cm1, c0, cp1; coef(Ty + ly, cm1, c0, cp1);
        const float2* a = &zs[(lz * 14 + ly) * 22 + lx];
        const int S = 22;
        float sx = (a[0].x + a[6 * S].x) + 3.f * (a[S].x + a[5 * S].x)
                 + cm1 * a[2 * S].x + c0 * a[3 * S].x + cp1 * a[4 * S].x;
        float sy = (a[0].y + a[6 * S].y) + 3.f * (a[S].y + a[5 * S].y)
                 + cm1 * a[2 * S].y + c0 * a[3 * S].y + cp1 * a[4 * S].y;
        ys[(lz * 8 + ly) * 22 + lx] = f2(sx * (1.f / 27.f), sy * (1.f / 27.f));
    }
    __syncthreads();

    // x-pass + division, write 16x8x8 outputs
    for (int u = t; u < 16 * 8 * 8; u += 512) {
        int x = u & 15, y = (u >> 4) & 7, z = u >> 7;
        float cm1, c0, cp1; coef(Tx + x, cm1, c0, cp1);
        const float2* a = &ys[(z * 8 + y) * 22 + x];
        float sx = (a[0].x + a[6].x) + 3.f * (a[1].x + a[5].x)
                 + cm1 * a[2].x + c0 * a[3].x + cp1 * a[4].x;
        float sy = (a[0].y + a[6].y) + 3.f * (a[1].y + a[5].y)
                 + cm1 * a[2].y + c0 * a[3].y + cp1 * a[4].y;
        ob[((size_t)z * NVOX + y) * NVOX + x] =
            (sx * (1.f / 27.f)) / (sy * (1.f / 27.f) + 0.001f);
    }
}

// ---------------------------------------------------------------------------
extern "C" void kernel_launch(void* const* d_in, const int* in_sizes, int n_in,
                              void* d_out, int out_size, void* d_ws, size_t ws_size,
                              hipStream_t stream)
{
    const float* q    = (const float*)d_in[0];
    const float* qval = (const float*)d_in[1];
    const float* w1   = (const float*)d_in[2];
    const float* b1   = (const float*)d_in[3];
    const float* w2   = (const float*)d_in[4];
    const float* b2   = (const float*)d_in[5];
    const float* w3   = (const float*)d_in[6];
    const float* b3   = (const float*)d_in[7];
    const float* w4   = (const float*)d_in[8];
    const float* b4   = (const float*)d_in[9];
    const float* w5   = (const float*)d_in[10];
    const float* b5   = (const float*)d_in[11];
    float* out = (float*)d_out;

    // ws layout:
    //   [0,      65536)  flags (16^3 tiles x 16 batches)
    //   [65536,  65540)  count
    //   [65552, 196624)  list (32768 ints)
    //   [196624,688144)  pts  (1920*16 float4)
    //   [688144,811024)  x1g  (1920*16 floats)
    unsigned char* flags = (unsigned char*)d_ws;
    int*    count = (int*)((char*)d_ws + 65536);
    int*    list  = (int*)((char*)d_ws + 65552);
    float4* pts   = (float4*)((char*)d_ws + 196624);
    float*  x1g   = (float*)((char*)d_ws + 688144);

    hipMemsetAsync(d_ws, 0, 65540, stream);

    zero_out<<<4096, 256, 0, stream>>>((float4*)out);

    mlp_stage1<<<240, 256, 0, stream>>>(q, w1, b1, x1g);

    mlp_tail<<<NB, 256, 0, stream>>>(x1g, qval, w2, b2, w3, b3,
                                     w4, b4, w5, b5, pts, flags);

    compact_tiles<<<NPAIRS / 256, 256, 0, stream>>>(flags, count, list);

    tile_active<<<NPAIRS, 512, 0, stream>>>(pts, count, list, out);
}